// Round 1
// 261.955 us; speedup vs baseline: 1.0193x; 1.0193x over previous
//
#include <hip/hip_runtime.h>

typedef _Float16 h8 __attribute__((ext_vector_type(8)));
typedef _Float16 h4 __attribute__((ext_vector_type(4)));
typedef float f4 __attribute__((ext_vector_type(4)));

typedef __attribute__((address_space(1))) const void GV;
typedef __attribute__((address_space(3))) void SV;

__device__ __forceinline__ void async16(const void* g, void* s) {
  __builtin_amdgcn_global_load_lds((GV*)g, (SV*)s, 16, 0, 0);
}

// x: (4,4096,1024) fp32; w_qkv: (3072,1024) fp32 rows e=h*192+d*3+t;
// mem_kv: (2,16,4,64) fp32; mask: (4,4096) int32; out: (4,4096,1024) fp32.
//
// xh/wh stored BANK-SWIZZLED: within each 128-B window of a row the eight
// 16-B chunks are permuted by ch ^= (row & 7); async16 staging lands this
// image in LDS verbatim -> conflict-free ds_read_b128 at BK=64.
// wh rows PERMUTED: [0,2048) = [h][k:64|v:64], [2048,3072) = [h][q:64].

#define XC 2097152   // x h8-chunks (16777216/8)
#define WC 393216    // w h8-chunks (3145728/8)

// ---------------- kernel 1: fp32 -> f16 convert; swizzle + W permute -----
__global__ __launch_bounds__(256) void cvt_f16(const float4* __restrict__ x,
                                               const float4* __restrict__ w,
                                               h8* __restrict__ xh,
                                               h8* __restrict__ wh) {
  int t = blockIdx.x * 256 + threadIdx.x;
  if (t < XC) {
    const int row = t >> 7, c7 = t & 127;
    const int dst = (row << 7) | (c7 & 120) | ((c7 & 7) ^ (row & 7));
    float4 a = x[t * 2], b = x[t * 2 + 1];
    h8 o = {(_Float16)a.x, (_Float16)a.y, (_Float16)a.z, (_Float16)a.w,
            (_Float16)b.x, (_Float16)b.y, (_Float16)b.z, (_Float16)b.w};
    xh[dst] = o;
  } else {
    const int u = t - XC;  // 0..393215
    const int rp = u >> 7, c7 = u & 127;
    int sr;
    if (rp < 2048) {
      int h = rp >> 7, c = rp & 127;
      sr = h * 192 + ((c < 64) ? (c * 3 + 1) : ((c - 64) * 3 + 2));
    } else {
      int q = rp - 2048;
      sr = (q >> 6) * 192 + (q & 63) * 3;
    }
    const int dst = (rp << 7) | (c7 & 120) | ((c7 & 7) ^ (rp & 7));
    float4 a = w[sr * 256 + c7 * 2], b = w[sr * 256 + c7 * 2 + 1];
    h8 o = {(_Float16)a.x, (_Float16)a.y, (_Float16)a.z, (_Float16)a.w,
            (_Float16)b.x, (_Float16)b.y, (_Float16)b.z, (_Float16)b.w};
    wh[dst] = o;
  }
}

// ---------------- kernel 2: fused qkv GEMM, 256^2 8-phase schedule -------
// grid (12 n-tiles, 64 m-tiles), 512 thr = 8 waves (2M x 4N), BK=64.
// LDS 128 KiB: 2 dbuf x (A 256x64 + B 256x64) f16. Counted vmcnt: per
// K-tile, 4 of next tile's loads issue inside phases, 4 of tile t+2 at the
// tail, then vmcnt(4) (never 0 until kt=14). Phases: Q00(ldA0,ldB0),
// Q01(ldB1,+stage), Q10(ldA1), Q11(+stage) -> A read once per mh-half.

__device__ __forceinline__ void ld4(h8 (&dst)[2][4], const _Float16* buf, int rbase,
                                    int l15, int quad, int swz) {
#pragma unroll
  for (int ks = 0; ks < 2; ++ks) {
    const int pc = ((((ks << 2) | quad) ^ swz)) << 3;
#pragma unroll
    for (int i = 0; i < 4; ++i)
      dst[ks][i] = *(const h8*)&buf[(rbase + i * 16 + l15) * 64 + pc];
  }
}

__device__ __forceinline__ void ld2(h8 (&dst)[2][2], const _Float16* buf, int rbase,
                                    int l15, int quad, int swz) {
#pragma unroll
  for (int ks = 0; ks < 2; ++ks) {
    const int pc = ((((ks << 2) | quad) ^ swz)) << 3;
#pragma unroll
    for (int j = 0; j < 2; ++j)
      dst[ks][j] = *(const h8*)&buf[(rbase + j * 16 + l15) * 64 + pc];
  }
}

template <int MH, int NH>
__device__ __forceinline__ void mq(f4 (&acc)[8][4], const h8 (&af)[2][4],
                                   const h8 (&bf)[2][2]) {
#pragma unroll
  for (int ks = 0; ks < 2; ++ks)
#pragma unroll
    for (int i = 0; i < 4; ++i)
#pragma unroll
      for (int j = 0; j < 2; ++j)
        acc[MH * 4 + i][NH * 2 + j] = __builtin_amdgcn_mfma_f32_16x16x32_f16(
            af[ks][i], bf[ks][j], acc[MH * 4 + i][NH * 2 + j], 0, 0, 0);
}

__device__ __forceinline__ void stage(const _Float16* g, _Float16* l, int it, int tid) {
  async16(g + (size_t)it * 65536, l + (it * 512 + tid) * 8);
}

__global__ __launch_bounds__(512, 2) void gemm_fused(const _Float16* __restrict__ A,
                                                     const _Float16* __restrict__ W,
                                                     const int* __restrict__ mask,
                                                     _Float16* __restrict__ P,
                                                     float* __restrict__ part) {
  __shared__ _Float16 smem[65536];  // 128 KiB
  _Float16* const As0 = smem;
  _Float16* const As1 = smem + 16384;
  _Float16* const Bs0 = smem + 32768;
  _Float16* const Bs1 = smem + 49152;
  const int tid = threadIdx.x;
  const int lane = tid & 63, wid = tid >> 6;
  const int wm = wid & 1, wn = wid >> 1;
  const int l15 = lane & 15, quad = lane >> 4;
  const int m0 = blockIdx.y * 256;
  const int n0 = blockIdx.x * 256;
  const int swz = l15 & 7;

  const int r0 = tid >> 3, cg = tid & 7;
  const _Float16* const Ab = A + (size_t)(m0 + r0) * 1024 + cg * 8;
  const _Float16* const Bb = W + (size_t)(n0 + r0) * 1024 + cg * 8;

  const f4 z = {0.f, 0.f, 0.f, 0.f};
  f4 acc[8][4];
#pragma unroll
  for (int i = 0; i < 8; ++i)
#pragma unroll
    for (int j = 0; j < 4; ++j) acc[i][j] = z;

  // prologue: tile0 fully, tile1 halves 0,1; keep tile1's 4 in flight
#pragma unroll
  for (int it = 0; it < 4; ++it) {
    stage(Ab, As0, it, tid);
    stage(Bb, Bs0, it, tid);
  }
  stage(Ab + 64, As1, 0, tid);
  stage(Bb + 64, Bs1, 0, tid);
  stage(Ab + 64, As1, 1, tid);
  stage(Bb + 64, Bs1, 1, tid);
  asm volatile("s_waitcnt vmcnt(4)" ::: "memory");
  __builtin_amdgcn_s_barrier();

#pragma unroll 2
  for (int kt = 0; kt < 16; ++kt) {
    _Float16* const Ac = (kt & 1) ? As1 : As0;
    _Float16* const Bc = (kt & 1) ? Bs1 : Bs0;
    _Float16* const An = (kt & 1) ? As0 : As1;
    _Float16* const Bn = (kt & 1) ? Bs0 : Bs1;
    const _Float16* const Anx = Ab + (kt + 1) * 64;
    const _Float16* const Bnx = Bb + (kt + 1) * 64;
    h8 af[2][4], bf0[2][2], bf1[2][2];
    const int arb = wm * 128, brb = wn * 64;

    // phase 0: Q00
    ld4(af, Ac, arb, l15, quad, swz);
    ld2(bf0, Bc, brb, l15, quad, swz);
    __builtin_amdgcn_s_barrier();
    asm volatile("s_waitcnt lgkmcnt(0)" ::: "memory");
    __builtin_amdgcn_s_setprio(1);
    mq<0, 0>(acc, af, bf0);
    __builtin_amdgcn_s_setprio(0);
    __builtin_amdgcn_s_barrier();

    // phase 1: Q01 (+stage next-tile half 2)
    ld2(bf1, Bc, brb + 32, l15, quad, swz);
    if (kt < 15) {
      stage(Anx, An, 2, tid);
      stage(Bnx, Bn, 2, tid);
    }
    __builtin_amdgcn_s_barrier();
    asm volatile("s_waitcnt lgkmcnt(0)" ::: "memory");
    __builtin_amdgcn_s_setprio(1);
    mq<0, 1>(acc, af, bf1);
    __builtin_amdgcn_s_setprio(0);
    __builtin_amdgcn_s_barrier();

    // phase 2: Q10
    ld4(af, Ac, arb + 64, l15, quad, swz);
    __builtin_amdgcn_s_barrier();
    asm volatile("s_waitcnt lgkmcnt(0)" ::: "memory");
    __builtin_amdgcn_s_setprio(1);
    mq<1, 0>(acc, af, bf0);
    __builtin_amdgcn_s_setprio(0);
    __builtin_amdgcn_s_barrier();

    // phase 3: Q11 (+stage next-tile half 3)
    if (kt < 15) {
      stage(Anx, An, 3, tid);
      stage(Bnx, Bn, 3, tid);
    }
    __builtin_amdgcn_s_barrier();
    __builtin_amdgcn_s_setprio(1);
    mq<1, 1>(acc, af, bf1);
    __builtin_amdgcn_s_setprio(0);
    __builtin_amdgcn_s_barrier();

    // tail: stage tile t+2 halves 0,1 into just-freed buffer; counted wait
    if (kt < 14) {
      const _Float16* const A2 = Ab + (kt + 2) * 64;
      const _Float16* const B2 = Bb + (kt + 2) * 64;
      stage(A2, Ac, 0, tid);
      stage(B2, Bc, 0, tid);
      stage(A2, Ac, 1, tid);
      stage(B2, Bc, 1, tid);
      asm volatile("s_waitcnt vmcnt(4)" ::: "memory");
      __builtin_amdgcn_s_barrier();
    } else if (kt == 14) {
      asm volatile("s_waitcnt vmcnt(0)" ::: "memory");
      __builtin_amdgcn_s_barrier();
    }
  }

  if (n0 < 2048) {
    // ---- kv epilogue: 2 heads per tile. wn: 0=ek(h0) 1=v(h0) 2=ek(h1) 3=v(h1)
    const int h0 = n0 >> 7;
    const int b = m0 >> 12;
    const int lc = (m0 & 4095) >> 8;  // 256-row chunk within batch, 0..15
    const int hh = wn >> 1, isv = wn & 1;
    // write ek/v into XOR-swizzled LDS [head][c:128][n:256]
#pragma unroll
    for (int i = 0; i < 8; ++i) {
      const int nb = wm * 128 + i * 16 + quad * 4;
      int mk[4];
      if (isv == 0) {
#pragma unroll
        for (int r = 0; r < 4; ++r) mk[r] = mask[m0 + nb + r];
      }
#pragma unroll
      for (int j = 0; j < 4; ++j) {
        const int cw = isv * 64 + j * 16 + l15;
        h4 o;
        if (isv == 0) {
#pragma unroll
          for (int r = 0; r < 4; ++r)
            o[r] = (_Float16)(mk[r] ? __expf(acc[i][j][r]) : 0.f);
        } else {
#pragma unroll
          for (int r = 0; r < 4; ++r) o[r] = (_Float16)acc[i][j][r];
        }
        *(h4*)&smem[(hh * 128 + cw) * 256 + (nb ^ (l15 * 8))] = o;
      }
    }
    __syncthreads();
    // ctx[d][e] = sum_n ek[n][d] v[n][e]; wave: head wid>>2, d-stripe (wid&3)*16
    f4 cacc[5];
#pragma unroll
    for (int i = 0; i < 5; ++i) cacc[i] = z;
    h8 bones;
    {
      const _Float16 o1 = (l15 == 0) ? (_Float16)1.f : (_Float16)0.f;
#pragma unroll
      for (int j = 0; j < 8; ++j) bones[j] = o1;
    }
    const int hw = wid >> 2, dsw = (wid & 3) * 16;
    const _Float16* const hb = &smem[hw * 128 * 256];
#pragma unroll
    for (int ks = 0; ks < 8; ++ks) {
      const int nb2 = (ks * 32 + quad * 8) ^ (l15 * 8);
      h8 a = *(const h8*)&hb[(dsw + l15) * 256 + nb2];
#pragma unroll
      for (int et = 0; et < 4; ++et) {
        h8 bv = *(const h8*)&hb[(64 + et * 16 + l15) * 256 + nb2];
        cacc[et] = __builtin_amdgcn_mfma_f32_16x16x32_f16(a, bv, cacc[et], 0, 0, 0);
      }
      cacc[4] = __builtin_amdgcn_mfma_f32_16x16x32_f16(a, bones, cacc[4], 0, 0, 0);
    }
    const int bh = b * 16 + h0 + hw;
    const size_t pb = ((size_t)bh * 16 + lc) * 4160;
    const int dw = dsw + quad * 4;
#pragma unroll
    for (int et = 0; et < 4; ++et)
#pragma unroll
      for (int r = 0; r < 4; ++r)
        part[pb + (size_t)(dw + r) * 64 + et * 16 + l15] = cacc[et][r];
    if (l15 == 0) {
#pragma unroll
      for (int r = 0; r < 4; ++r) part[pb + 4096 + dw + r] = cacc[4][r];
    }
  } else {
    // ---- q epilogue: P = exp(q/8), n-major scalar stores ----
    const int q0 = (n0 - 2048) + wn * 64;
#pragma unroll
    for (int i = 0; i < 8; ++i) {
      const int rg = m0 + wm * 128 + i * 16 + quad * 4;
#pragma unroll
      for (int j = 0; j < 4; ++j) {
        const int qc = q0 + j * 16 + l15;  // = h*64+d
#pragma unroll
        for (int r = 0; r < 4; ++r)
          P[(size_t)(rg + r) * 1024 + qc] = (_Float16)__expf(acc[i][j][r] * 0.125f);
      }
    }
  }
}

// ---------------- kernel 3: reduce partials + memkv, store ctx^T ---------
// grid (64 bh, 16 d-slices). part: per (bh, 16 chunks of 256 rows) 4160 fl.
__global__ __launch_bounds__(256) void reduce_ctx(const float* __restrict__ part,
                                                  const float* __restrict__ memkv,
                                                  _Float16* __restrict__ ctxt) {
  const int bh = blockIdx.x;
  const int dsl = blockIdx.y;
  const int h = bh & 15;
  const int tid = threadIdx.x;
  const int dl = tid >> 6, e = tid & 63;
  const int d = dsl * 4 + dl;
  const size_t pb = (size_t)bh * 16 * 4160;

  float den = 0.f;
#pragma unroll 8
  for (int c = 0; c < 16; ++c) den += part[pb + (size_t)c * 4160 + 4096 + d];
  float s = 0.f;
#pragma unroll 8
  for (int c = 0; c < 16; ++c) s += part[pb + (size_t)c * 4160 + (size_t)d * 64 + e];
#pragma unroll
  for (int j = 0; j < 4; ++j) {
    const float ek = __expf(memkv[(h * 4 + j) * 64 + d]);
    den += ek;
    s += ek * memkv[4096 + (h * 4 + j) * 64 + e];
  }
  ctxt[(size_t)bh * 4096 + (size_t)e * 64 + d] = (_Float16)(s / den);
}

// ---------------- kernel 4: out = (P @ ctx)/s, register-direct MFMA ------
// grid (128 l-chunks, 16 heads). No LDS, no barriers.
__global__ __launch_bounds__(256) void attn_out(const _Float16* __restrict__ P,
                                                const _Float16* __restrict__ ctxt,
                                                const int* __restrict__ mask,
                                                float* __restrict__ out) {
  const int l0 = blockIdx.x * 128;
  const int h = blockIdx.y;
  const int bh = (l0 >> 12) * 16 + h;
  const int tid = threadIdx.x;
  const int lane = tid & 63, wid = tid >> 6;
  const int l15 = lane & 15, quad = lane >> 4;

  h8 af[2][2], bf[2][4], bones;
  {
    const _Float16 o1 = (l15 == 0) ? (_Float16)1.f : (_Float16)0.f;
#pragma unroll
    for (int j = 0; j < 8; ++j) bones[j] = o1;
  }
#pragma unroll
  for (int i = 0; i < 2; ++i)
#pragma unroll
    for (int ks = 0; ks < 2; ++ks)
      af[i][ks] = *(const h8*)&P[(size_t)(l0 + wid * 32 + i * 16 + l15) * 1024 +
                                 h * 64 + ks * 32 + quad * 8];
#pragma unroll
  for (int ks = 0; ks < 2; ++ks)
#pragma unroll
    for (int et = 0; et < 4; ++et)
      bf[ks][et] = *(const h8*)&ctxt[(size_t)bh * 4096 +
                                     (size_t)(et * 16 + l15) * 64 + ks * 32 + quad * 8];

  const f4 z = {0.f, 0.f, 0.f, 0.f};
  f4 acc[2][5];
#pragma unroll
  for (int i = 0; i < 2; ++i)
#pragma unroll
    for (int j = 0; j < 5; ++j) acc[i][j] = z;
#pragma unroll
  for (int i = 0; i < 2; ++i)
#pragma unroll
    for (int ks = 0; ks < 2; ++ks) {
#pragma unroll
      for (int et = 0; et < 4; ++et)
        acc[i][et] = __builtin_amdgcn_mfma_f32_16x16x32_f16(af[i][ks], bf[ks][et], acc[i][et], 0, 0, 0);
      acc[i][4] = __builtin_amdgcn_mfma_f32_16x16x32_f16(af[i][ks], bones, acc[i][4], 0, 0, 0);
    }

#pragma unroll
  for (int i = 0; i < 2; ++i) {
#pragma unroll
    for (int r = 0; r < 4; ++r) {
      const int row = l0 + wid * 32 + i * 16 + quad * 4 + r;
      const float sb = __shfl(acc[i][4][r], lane & 48);  // den from col-0 lane
      const float iv = mask[row] ? 1.0f / sb : 0.0f;
#pragma unroll
      for (int et = 0; et < 4; ++et)
        out[(size_t)row * 1024 + h * 64 + et * 16 + l15] = acc[i][et][r] * iv;
    }
  }
}

// ---------------- launch ----------------
extern "C" void kernel_launch(void* const* d_in, const int* in_sizes, int n_in,
                              void* d_out, int out_size, void* d_ws, size_t ws_size,
                              hipStream_t stream) {
  const float* x = (const float*)d_in[0];      // 16777216
  const float* w = (const float*)d_in[1];      // 3145728
  const float* memkv = (const float*)d_in[2];  // 8192
  const int* mask = (const int*)d_in[3];       // 16384
  float* out = (float*)d_out;

  char* ws = (char*)d_ws;
  _Float16* xh   = (_Float16*)(ws + 0);           //  33,554,432 (swizzled)
  _Float16* wh   = (_Float16*)(ws + 33554432);    //   6,291,456 (permuted+swizzled)
  _Float16* P    = (_Float16*)(ws + 39845888);    //  33,554,432
  float*    part = (float*)(ws + 73400320);       //  17,039,360 (16 chunks)
  _Float16* ctxt = (_Float16*)(ws + 107479040);   //     524,288

  cvt_f16<<<dim3(9728), dim3(256), 0, stream>>>((const float4*)x, (const float4*)w,
                                                (h8*)xh, (h8*)wh);
  gemm_fused<<<dim3(12, 64), dim3(512), 0, stream>>>(xh, wh, mask, P, part);
  reduce_ctx<<<dim3(64, 16), dim3(256), 0, stream>>>(part, memkv, ctxt);
  attn_out<<<dim3(128, 16), dim3(256), 0, stream>>>(P, ctxt, mask, out);
}

// Round 4
// 260.366 us; speedup vs baseline: 1.0255x; 1.0061x over previous
//
#include <hip/hip_runtime.h>

typedef _Float16 h8 __attribute__((ext_vector_type(8)));
typedef _Float16 h4 __attribute__((ext_vector_type(4)));
typedef float f4 __attribute__((ext_vector_type(4)));

typedef __attribute__((address_space(1))) const void GV;
typedef __attribute__((address_space(3))) void SV;

__device__ __forceinline__ void async16(const void* g, void* s) {
  __builtin_amdgcn_global_load_lds((GV*)g, (SV*)s, 16, 0, 0);
}

// x: (4,4096,1024) fp32; w_qkv: (3072,1024) fp32 rows e=h*192+d*3+t;
// mem_kv: (2,16,4,64) fp32; mask: (4,4096) int32; out: (4,4096,1024) fp32.
//
// xh/wh stored BANK-SWIZZLED: within each 128-B window of a row the eight
// 16-B chunks are permuted by ch ^= (row & 7); async16 staging lands this
// image in LDS verbatim -> conflict-free ds_read_b128 at BK=64.
// wh rows PERMUTED: [0,2048) = [h][k:64|v:64], [2048,3072) = [h][q:64].

#define XC 2097152   // x h8-chunks (16777216/8)
#define WC 393216    // w h8-chunks (3145728/8)

// ---------------- kernel 1: fp32 -> f16 convert; swizzle + W permute -----
__global__ __launch_bounds__(256) void cvt_f16(const float4* __restrict__ x,
                                               const float4* __restrict__ w,
                                               h8* __restrict__ xh,
                                               h8* __restrict__ wh) {
  int t = blockIdx.x * 256 + threadIdx.x;
  if (t < XC) {
    const int row = t >> 7, c7 = t & 127;
    const int dst = (row << 7) | (c7 & 120) | ((c7 & 7) ^ (row & 7));
    float4 a = x[t * 2], b = x[t * 2 + 1];
    h8 o = {(_Float16)a.x, (_Float16)a.y, (_Float16)a.z, (_Float16)a.w,
            (_Float16)b.x, (_Float16)b.y, (_Float16)b.z, (_Float16)b.w};
    xh[dst] = o;
  } else {
    const int u = t - XC;  // 0..393215
    const int rp = u >> 7, c7 = u & 127;
    int sr;
    if (rp < 2048) {
      int h = rp >> 7, c = rp & 127;
      sr = h * 192 + ((c < 64) ? (c * 3 + 1) : ((c - 64) * 3 + 2));
    } else {
      int q = rp - 2048;
      sr = (q >> 6) * 192 + (q & 63) * 3;
    }
    const int dst = (rp << 7) | (c7 & 120) | ((c7 & 7) ^ (rp & 7));
    float4 a = w[sr * 256 + c7 * 2], b = w[sr * 256 + c7 * 2 + 1];
    h8 o = {(_Float16)a.x, (_Float16)a.y, (_Float16)a.z, (_Float16)a.w,
            (_Float16)b.x, (_Float16)b.y, (_Float16)b.z, (_Float16)b.w};
    wh[dst] = o;
  }
}

// ---------------- kernel 2: fused qkv GEMM, 256^2 8-phase schedule -------
// grid (12 n-tiles, 64 m-tiles), 512 thr = 8 waves (2M x 4N), BK=64.
// LDS 128 KiB: 2 dbuf x (A 256x64 + B 256x64) f16.
// Staging cadence (race-free from the barrier graph):
//   All B ds_reads of tile t retire by p1's trailing barrier; all A
//   ds_reads by p2's trailing barrier. So tile t+2 (same buffer parity
//   as t) stages B at p2 and A at p3. Counted wait: vmcnt(8) at p3 end
//   forces tile t+1's 8 loads (issued one full K-tile earlier) while
//   leaving t+2's 8 in flight. vmcnt(0) only at kt=14.

__device__ __forceinline__ void ld4(h8 (&dst)[2][4], const _Float16* buf, int rbase,
                                    int l15, int quad, int swz) {
#pragma unroll
  for (int ks = 0; ks < 2; ++ks) {
    const int pc = ((((ks << 2) | quad) ^ swz)) << 3;
#pragma unroll
    for (int i = 0; i < 4; ++i)
      dst[ks][i] = *(const h8*)&buf[(rbase + i * 16 + l15) * 64 + pc];
  }
}

__device__ __forceinline__ void ld2(h8 (&dst)[2][2], const _Float16* buf, int rbase,
                                    int l15, int quad, int swz) {
#pragma unroll
  for (int ks = 0; ks < 2; ++ks) {
    const int pc = ((((ks << 2) | quad) ^ swz)) << 3;
#pragma unroll
    for (int j = 0; j < 2; ++j)
      dst[ks][j] = *(const h8*)&buf[(rbase + j * 16 + l15) * 64 + pc];
  }
}

template <int MH, int NH>
__device__ __forceinline__ void mq(f4 (&acc)[8][4], const h8 (&af)[2][4],
                                   const h8 (&bf)[2][2]) {
#pragma unroll
  for (int ks = 0; ks < 2; ++ks)
#pragma unroll
    for (int i = 0; i < 4; ++i)
#pragma unroll
      for (int j = 0; j < 2; ++j)
        acc[MH * 4 + i][NH * 2 + j] = __builtin_amdgcn_mfma_f32_16x16x32_f16(
            af[ks][i], bf[ks][j], acc[MH * 4 + i][NH * 2 + j], 0, 0, 0);
}

__device__ __forceinline__ void stage(const _Float16* g, _Float16* l, int it, int tid) {
  async16(g + (size_t)it * 65536, l + (it * 512 + tid) * 8);
}

__global__ __launch_bounds__(512, 2) void gemm_fused(const _Float16* __restrict__ A,
                                                     const _Float16* __restrict__ W,
                                                     const int* __restrict__ mask,
                                                     _Float16* __restrict__ P,
                                                     float* __restrict__ part) {
  __shared__ _Float16 smem[65536];  // 128 KiB
  _Float16* const As0 = smem;
  _Float16* const As1 = smem + 16384;
  _Float16* const Bs0 = smem + 32768;
  _Float16* const Bs1 = smem + 49152;
  const int tid = threadIdx.x;
  const int lane = tid & 63, wid = tid >> 6;
  const int wm = wid & 1, wn = wid >> 1;
  const int l15 = lane & 15, quad = lane >> 4;
  const int m0 = blockIdx.y * 256;
  const int n0 = blockIdx.x * 256;
  const int swz = l15 & 7;

  const int r0 = tid >> 3, cg = tid & 7;
  const _Float16* const Ab = A + (size_t)(m0 + r0) * 1024 + cg * 8;
  const _Float16* const Bb = W + (size_t)(n0 + r0) * 1024 + cg * 8;

  const f4 z = {0.f, 0.f, 0.f, 0.f};
  f4 acc[8][4];
#pragma unroll
  for (int i = 0; i < 8; ++i)
#pragma unroll
    for (int j = 0; j < 4; ++j) acc[i][j] = z;

  // prologue: tile0 (8 loads) then tile1 (8 loads); wait tile0, keep tile1
#pragma unroll
  for (int it = 0; it < 4; ++it) {
    stage(Ab, As0, it, tid);
    stage(Bb, Bs0, it, tid);
  }
#pragma unroll
  for (int it = 0; it < 4; ++it) {
    stage(Ab + 64, As1, it, tid);
    stage(Bb + 64, Bs1, it, tid);
  }
  asm volatile("s_waitcnt vmcnt(8)" ::: "memory");
  __builtin_amdgcn_s_barrier();

#pragma unroll 2
  for (int kt = 0; kt < 16; ++kt) {
    _Float16* const Ac = (kt & 1) ? As1 : As0;
    _Float16* const Bc = (kt & 1) ? Bs1 : Bs0;
    const _Float16* const Ax2 = Ab + (kt + 2) * 64;
    const _Float16* const Bx2 = Bb + (kt + 2) * 64;
    h8 af[2][4], bf0[2][2], bf1[2][2];
    const int arb = wm * 128, brb = wn * 64;

    // p0: Q00 — ld af-lo + bf0
    ld4(af, Ac, arb, l15, quad, swz);
    ld2(bf0, Bc, brb, l15, quad, swz);
    asm volatile("s_waitcnt lgkmcnt(8)" ::: "memory");
    __builtin_amdgcn_s_barrier();
    asm volatile("s_waitcnt lgkmcnt(0)" ::: "memory");
    __builtin_amdgcn_s_setprio(1);
    mq<0, 0>(acc, af, bf0);
    __builtin_amdgcn_s_setprio(0);
    __builtin_amdgcn_s_barrier();

    // p1: Q01 — ld bf1 (last B read of tile t)
    ld2(bf1, Bc, brb + 32, l15, quad, swz);
    __builtin_amdgcn_s_barrier();
    asm volatile("s_waitcnt lgkmcnt(0)" ::: "memory");
    __builtin_amdgcn_s_setprio(1);
    mq<0, 1>(acc, af, bf1);
    __builtin_amdgcn_s_setprio(0);
    __builtin_amdgcn_s_barrier();

    // p2: Q10 — ld af-hi (last A read); B region of cur buf now free:
    //            stage B(t+2) into Bc
    ld4(af, Ac, arb + 64, l15, quad, swz);
    if (kt < 14) {
#pragma unroll
      for (int it = 0; it < 4; ++it) stage(Bx2, Bc, it, tid);
    }
    __builtin_amdgcn_s_barrier();
    asm volatile("s_waitcnt lgkmcnt(0)" ::: "memory");
    __builtin_amdgcn_s_setprio(1);
    mq<1, 0>(acc, af, bf0);
    __builtin_amdgcn_s_setprio(0);
    __builtin_amdgcn_s_barrier();

    // p3: Q11 — A region of cur buf now free: stage A(t+2) into Ac;
    //            counted vmcnt(8) forces tile t+1's loads only
    if (kt < 14) {
#pragma unroll
      for (int it = 0; it < 4; ++it) stage(Ax2, Ac, it, tid);
    }
    __builtin_amdgcn_s_barrier();
    __builtin_amdgcn_s_setprio(1);
    mq<1, 1>(acc, af, bf1);
    __builtin_amdgcn_s_setprio(0);
    if (kt < 14) {
      asm volatile("s_waitcnt vmcnt(8)" ::: "memory");
    } else if (kt == 14) {
      asm volatile("s_waitcnt vmcnt(0)" ::: "memory");
    }
    __builtin_amdgcn_s_barrier();
  }

  if (n0 < 2048) {
    // ---- kv epilogue: 2 heads per tile. wn: 0=ek(h0) 1=v(h0) 2=ek(h1) 3=v(h1)
    const int h0 = n0 >> 7;
    const int b = m0 >> 12;
    const int lc = (m0 & 4095) >> 8;  // 256-row chunk within batch, 0..15
    const int hh = wn >> 1, isv = wn & 1;
    // write ek/v into XOR-swizzled LDS [head][c:128][n:256]
#pragma unroll
    for (int i = 0; i < 8; ++i) {
      const int nb = wm * 128 + i * 16 + quad * 4;
      int mk[4];
      if (isv == 0) {
#pragma unroll
        for (int r = 0; r < 4; ++r) mk[r] = mask[m0 + nb + r];
      }
#pragma unroll
      for (int j = 0; j < 4; ++j) {
        const int cw = isv * 64 + j * 16 + l15;
        h4 o;
        if (isv == 0) {
#pragma unroll
          for (int r = 0; r < 4; ++r)
            o[r] = (_Float16)(mk[r] ? __expf(acc[i][j][r]) : 0.f);
        } else {
#pragma unroll
          for (int r = 0; r < 4; ++r) o[r] = (_Float16)acc[i][j][r];
        }
        *(h4*)&smem[(hh * 128 + cw) * 256 + (nb ^ (l15 * 8))] = o;
      }
    }
    __syncthreads();
    // ctx[d][e] = sum_n ek[n][d] v[n][e]; wave: head wid>>2, d-stripe (wid&3)*16
    f4 cacc[5];
#pragma unroll
    for (int i = 0; i < 5; ++i) cacc[i] = z;
    h8 bones;
    {
      const _Float16 o1 = (l15 == 0) ? (_Float16)1.f : (_Float16)0.f;
#pragma unroll
      for (int j = 0; j < 8; ++j) bones[j] = o1;
    }
    const int hw = wid >> 2, dsw = (wid & 3) * 16;
    const _Float16* const hb = &smem[hw * 128 * 256];
#pragma unroll
    for (int ks = 0; ks < 8; ++ks) {
      const int nb2 = (ks * 32 + quad * 8) ^ (l15 * 8);
      h8 a = *(const h8*)&hb[(dsw + l15) * 256 + nb2];
#pragma unroll
      for (int et = 0; et < 4; ++et) {
        h8 bv = *(const h8*)&hb[(64 + et * 16 + l15) * 256 + nb2];
        cacc[et] = __builtin_amdgcn_mfma_f32_16x16x32_f16(a, bv, cacc[et], 0, 0, 0);
      }
      cacc[4] = __builtin_amdgcn_mfma_f32_16x16x32_f16(a, bones, cacc[4], 0, 0, 0);
    }
    const int bh = b * 16 + h0 + hw;
    const size_t pb = ((size_t)bh * 16 + lc) * 4160;
    const int dw = dsw + quad * 4;
#pragma unroll
    for (int et = 0; et < 4; ++et)
#pragma unroll
      for (int r = 0; r < 4; ++r)
        part[pb + (size_t)(dw + r) * 64 + et * 16 + l15] = cacc[et][r];
    if (l15 == 0) {
#pragma unroll
      for (int r = 0; r < 4; ++r) part[pb + 4096 + dw + r] = cacc[4][r];
    }
  } else {
    // ---- q epilogue: P = exp(q/8), n-major scalar stores ----
    const int q0 = (n0 - 2048) + wn * 64;
#pragma unroll
    for (int i = 0; i < 8; ++i) {
      const int rg = m0 + wm * 128 + i * 16 + quad * 4;
#pragma unroll
      for (int j = 0; j < 4; ++j) {
        const int qc = q0 + j * 16 + l15;  // = h*64+d
#pragma unroll
        for (int r = 0; r < 4; ++r)
          P[(size_t)(rg + r) * 1024 + qc] = (_Float16)__expf(acc[i][j][r] * 0.125f);
      }
    }
  }
}

// ---------------- kernel 3: reduce partials + memkv, store ctx^T ---------
// grid (64 bh, 16 d-slices). part: per (bh, 16 chunks of 256 rows) 4160 fl.
__global__ __launch_bounds__(256) void reduce_ctx(const float* __restrict__ part,
                                                  const float* __restrict__ memkv,
                                                  _Float16* __restrict__ ctxt) {
  const int bh = blockIdx.x;
  const int dsl = blockIdx.y;
  const int h = bh & 15;
  const int tid = threadIdx.x;
  const int dl = tid >> 6, e = tid & 63;
  const int d = dsl * 4 + dl;
  const size_t pb = (size_t)bh * 16 * 4160;

  float den = 0.f;
#pragma unroll 8
  for (int c = 0; c < 16; ++c) den += part[pb + (size_t)c * 4160 + 4096 + d];
  float s = 0.f;
#pragma unroll 8
  for (int c = 0; c < 16; ++c) s += part[pb + (size_t)c * 4160 + (size_t)d * 64 + e];
#pragma unroll
  for (int j = 0; j < 4; ++j) {
    const float ek = __expf(memkv[(h * 4 + j) * 64 + d]);
    den += ek;
    s += ek * memkv[4096 + (h * 4 + j) * 64 + e];
  }
  ctxt[(size_t)bh * 4096 + (size_t)e * 64 + d] = (_Float16)(s / den);
}

// ---------------- kernel 4: out = (P @ ctx)/s, register-direct MFMA ------
// grid (128 l-chunks, 16 heads). No LDS, no barriers.
__global__ __launch_bounds__(256) void attn_out(const _Float16* __restrict__ P,
                                                const _Float16* __restrict__ ctxt,
                                                const int* __restrict__ mask,
                                                float* __restrict__ out) {
  const int l0 = blockIdx.x * 128;
  const int h = blockIdx.y;
  const int bh = (l0 >> 12) * 16 + h;
  const int tid = threadIdx.x;
  const int lane = tid & 63, wid = tid >> 6;
  const int l15 = lane & 15, quad = lane >> 4;

  h8 af[2][2], bf[2][4], bones;
  {
    const _Float16 o1 = (l15 == 0) ? (_Float16)1.f : (_Float16)0.f;
#pragma unroll
    for (int j = 0; j < 8; ++j) bones[j] = o1;
  }
#pragma unroll
  for (int i = 0; i < 2; ++i)
#pragma unroll
    for (int ks = 0; ks < 2; ++ks)
      af[i][ks] = *(const h8*)&P[(size_t)(l0 + wid * 32 + i * 16 + l15) * 1024 +
                                 h * 64 + ks * 32 + quad * 8];
#pragma unroll
  for (int ks = 0; ks < 2; ++ks)
#pragma unroll
    for (int et = 0; et < 4; ++et)
      bf[ks][et] = *(const h8*)&ctxt[(size_t)bh * 4096 +
                                     (size_t)(et * 16 + l15) * 64 + ks * 32 + quad * 8];

  const f4 z = {0.f, 0.f, 0.f, 0.f};
  f4 acc[2][5];
#pragma unroll
  for (int i = 0; i < 2; ++i)
#pragma unroll
    for (int j = 0; j < 5; ++j) acc[i][j] = z;
#pragma unroll
  for (int i = 0; i < 2; ++i)
#pragma unroll
    for (int ks = 0; ks < 2; ++ks) {
#pragma unroll
      for (int et = 0; et < 4; ++et)
        acc[i][et] = __builtin_amdgcn_mfma_f32_16x16x32_f16(af[i][ks], bf[ks][et], acc[i][et], 0, 0, 0);
      acc[i][4] = __builtin_amdgcn_mfma_f32_16x16x32_f16(af[i][ks], bones, acc[i][4], 0, 0, 0);
    }

#pragma unroll
  for (int i = 0; i < 2; ++i) {
#pragma unroll
    for (int r = 0; r < 4; ++r) {
      const int row = l0 + wid * 32 + i * 16 + quad * 4 + r;
      const float sb = __shfl(acc[i][4][r], lane & 48);  // den from col-0 lane
      const float iv = mask[row] ? 1.0f / sb : 0.0f;
#pragma unroll
      for (int et = 0; et < 4; ++et)
        out[(size_t)row * 1024 + h * 64 + et * 16 + l15] = acc[i][et][r] * iv;
    }
  }
}

// ---------------- launch ----------------
extern "C" void kernel_launch(void* const* d_in, const int* in_sizes, int n_in,
                              void* d_out, int out_size, void* d_ws, size_t ws_size,
                              hipStream_t stream) {
  const float* x = (const float*)d_in[0];      // 16777216
  const float* w = (const float*)d_in[1];      // 3145728
  const float* memkv = (const float*)d_in[2];  // 8192
  const int* mask = (const int*)d_in[3];       // 16384
  float* out = (float*)d_out;

  char* ws = (char*)d_ws;
  _Float16* xh   = (_Float16*)(ws + 0);           //  33,554,432 (swizzled)
  _Float16* wh   = (_Float16*)(ws + 33554432);    //   6,291,456 (permuted+swizzled)
  _Float16* P    = (_Float16*)(ws + 39845888);    //  33,554,432
  float*    part = (float*)(ws + 73400320);       //  17,039,360 (16 chunks)
  _Float16* ctxt = (_Float16*)(ws + 107479040);   //     524,288

  cvt_f16<<<dim3(9728), dim3(256), 0, stream>>>((const float4*)x, (const float4*)w,
                                                (h8*)xh, (h8*)wh);
  gemm_fused<<<dim3(12, 64), dim3(512), 0, stream>>>(xh, wh, mask, P, part);
  reduce_ctx<<<dim3(64, 16), dim3(256), 0, stream>>>(part, memkv, ctxt);
  attn_out<<<dim3(128, 16), dim3(256), 0, stream>>>(P, ctxt, mask, out);
}